// Round 1
// baseline (120.406 us; speedup 1.0000x reference)
//
#include <hip/hip_runtime.h>
#include <math.h>

// N=1024, C=128, H=4, HD=32, HID=64
//   u[n,m]   = pos[n,:] @ W1[:,m]       (hid[i,j,m] = (u[i,m]+b1[m]) - u[j,m])
//   A[n,h,m] = sum_d q[n,h*32+d] * W2[m, h*32+d]
//   c[n,h]   = sum_d q[n,h*32+d] * b2[h*32+d]
//   score[h,i,j] = (q_i.k_j)/sqrt(32) + sum_m relu(hid)*A[i,h,m] + c[i,h] - dist(i,j)
//   softmax via exp2 (q pre-scaled RS*log2e; A/c/pos pre-scaled log2e)
//   k and u streams stored as packed bf16 pairs (RNE).
//
// R11: k_attn blocks now cover 4 i-rows (256 blocks x 1024 thr), geom and qk
//   accumulate into the SAME registers (they were summed before exp anyway),
//   __launch_bounds__(1024,4) -> 128 VGPRs. Halves per-block-amortized L2
//   j-stream traffic (kTb+uTb+v: 459 -> 230 MB) and removes the 64-VGPR
//   accumulator squeeze of the old (1024,8) version. LDS 136 KB -> 1 blk/CU.
//
// ws layout (floats):
//   q    [1024][128]  (x RSL)                         @ 0
//   v    [1024][128]                                  @ 131072
//   kTb  u32[32][1024][2]: bf16x2 k quads             @ 262144
//   uTb  u32[16][1024][2]: bf16x2 u quads             @ 327680
//   sA   [1024][328]                                  @ 360448
//   pos4 [1024][4] (x L2E)                            @ 696320

typedef float v2f __attribute__((ext_vector_type(2)));
typedef float v4f __attribute__((ext_vector_type(4)));

#define L2E 1.4426950408889634f
#define RSL (0.17677669529663687f * L2E)

static __device__ __forceinline__ float dot4(float4 a, float4 b) {
  return a.x*b.x + a.y*b.y + a.z*b.z + a.w*b.w;
}
static __device__ __forceinline__ v2f fma2(v2f a, v2f b, v2f c) {
  return __builtin_elementwise_fma(a, b, c);
}
static __device__ __forceinline__ v4f fma4s(float s, v4f b, v4f c) {
  v4f sv = {s, s, s, s};
  return __builtin_elementwise_fma(sv, b, c);
}
static __device__ __forceinline__ unsigned int bfr(float f) {   // fp32 -> bf16 (RNE)
  unsigned int b = __float_as_uint(f);
  return (b + 0x7fffu + ((b >> 16) & 1u)) >> 16;
}
static __device__ __forceinline__ unsigned int pack2(float lo, float hi) {
  return bfr(lo) | (bfr(hi) << 16);
}
static __device__ __forceinline__ v2f unpk(unsigned int a) {    // bf16x2 -> 2x fp32
  v2f r;
  r.x = __uint_as_float(a << 16);
  r.y = __uint_as_float(a & 0xffff0000u);
  return r;
}

// ---------------- K1: precompute (unchanged) -------------------------------
// 512 blocks x 384 thr; block = 2 rows.
__global__ __launch_bounds__(384) void k_pre(
    const float* __restrict__ x, const float* __restrict__ y, const float* __restrict__ pos,
    const float* __restrict__ Wq, const float* __restrict__ bq,
    const float* __restrict__ Wk, const float* __restrict__ bk,
    const float* __restrict__ Wv, const float* __restrict__ bv,
    const float* __restrict__ W1, const float* __restrict__ b1,
    const float* __restrict__ W2, const float* __restrict__ b2,
    float* __restrict__ q, float* __restrict__ v,
    unsigned int* __restrict__ kTb, unsigned int* __restrict__ uTb,
    float* __restrict__ sA, float* __restrict__ pos4w)
{
  __shared__ float xs[256], ys[256], qs[256];
  __shared__ __align__(16) float4 W2S[64*33];

  const int t  = threadIdx.x;
  const int n0 = blockIdx.x * 2;

  if (t < 256) { xs[t] = x[n0*128 + t]; ys[t] = y[n0*128 + t]; }
  {
    const float4* w2g = (const float4*)W2;
    #pragma unroll
    for (int r = 0; r < 6; ++r) {
      const int e = t + 384*r;
      if (e < 2048) W2S[(e>>5)*33 + (e&31)] = w2g[e];
    }
  }
  __syncthreads();

  {
    const int c   = t & 127;
    const int mat = t >> 7;                 // wave-uniform
    const float* W    = (mat == 0) ? Wq : (mat == 1 ? Wk : Wv);
    const float* S    = (mat == 0) ? xs : ys;
    const float* bias = (mat == 0) ? bq : (mat == 1 ? bk : bv);
    float a0 = 0.f, a1 = 0.f;
    #pragma unroll 8
    for (int d = 0; d < 128; ++d) {
      const float w_ = W[d*128 + c];
      a0 = fmaf(S[d],       w_, a0);
      a1 = fmaf(S[128 + d], w_, a1);
    }
    const float bb = bias[c];
    a0 += bb; a1 += bb;
    if (mat == 0) {
      q[n0*128 + c] = a0 * RSL; q[(n0+1)*128 + c] = a1 * RSL;
      qs[c] = a0; qs[128 + c] = a1;
    } else if (mat == 2) {
      v[n0*128 + c] = a0; v[(n0+1)*128 + c] = a1;
    } else {
      // k: pack adjacent columns into bf16x2 via in-wave exchange
      const float b0 = __shfl_xor(a0, 1);
      const float b1 = __shfl_xor(a1, 1);
      if ((c & 1) == 0) {
        const int idx = ((c>>2)*1024)*2 + ((c>>1)&1);
        kTb[idx + (n0  )*2] = pack2(a0, b0);
        kTb[idx + (n0+1)*2] = pack2(a1, b1);
      }
    }
  }
  __syncthreads();

  if (t < 256) {
    const int m = t & 63, h = t >> 6;
    const float4* qs4 = (const float4*)qs;
    #pragma unroll
    for (int ii = 0; ii < 2; ++ii) {
      float acc = 0.f;
      #pragma unroll
      for (int ch = 0; ch < 8; ++ch)
        acc += dot4(qs4[ii*32 + h*8 + ch], W2S[m*33 + h*8 + ch]);
      sA[(n0+ii)*328 + 8 + (m>>2)*20 + h*4 + (m&3)] = acc * L2E;
    }
    if (t < 8) {
      const int ii = t >> 2, h2 = t & 3;
      float ca = 0.f;
      #pragma unroll
      for (int d = 0; d < 32; ++d) ca = fmaf(qs[ii*128 + h2*32 + d], b2[h2*32 + d], ca);
      sA[(n0+ii)*328 + h2] = ca * L2E;
    } else if (t < 16) {
      const int tt = t-8, ii = tt>>2, cc = tt&3;
      sA[(n0+ii)*328 + 4 + cc] = (cc < 3) ? pos[(n0+ii)*3 + cc] * L2E : 0.f;
    } else if (t < 24) {
      const int tt = t-16, ii = tt>>2, cc = tt&3;
      pos4w[(n0+ii)*4 + cc] = (cc < 3) ? pos[(n0+ii)*3 + cc] * L2E : 0.f;
    }
  } else if (t < 320) {
    // u: thread = (ii, m-pair); computes 2 adjacent m -> one bf16x2 word
    const int tt = t - 256, ii = tt >> 5, mp = tt & 31;
    const int m0 = mp * 2;
    float ua0 = 0.f, ua1 = 0.f;
    #pragma unroll
    for (int cc = 0; cc < 3; ++cc) {
      const float p = pos[(n0+ii)*3 + cc];
      ua0 = fmaf(p, W1[cc*64 + m0    ], ua0);
      ua1 = fmaf(p, W1[cc*64 + m0 + 1], ua1);
    }
    sA[(n0+ii)*328 + 8 + (m0>>2)*20 + 16 + (m0&3)    ] = ua0 + b1[m0];
    sA[(n0+ii)*328 + 8 + (m0>>2)*20 + 16 + (m0&3) + 1] = ua1 + b1[m0+1];
    uTb[((mp>>1)*1024 + (n0+ii))*2 + (mp&1)] = pack2(ua0, ua1);
  }
}

// ---------------- K2: fused scores + softmax + PV + direct out -------------
// 256 blocks x 1024 thr (16 waves). Block = 4 i-rows x ALL j; wave w = j-tile w.
// geom and qk accumulate into the SAME score registers (merged accumulators).
__global__ __launch_bounds__(1024, 4) void k_attn(
    const float* __restrict__ q, const float* __restrict__ v,
    const uint2* __restrict__ kTb, const uint2* __restrict__ uTb,
    const float* __restrict__ sA, const v4f* __restrict__ pos4,
    float* __restrict__ out)
{
  __shared__ __align__(16) float eL[16*1088];  // per-wave E: [(ii*4+h)*68 + j]  (69.6 KB)
  __shared__ __align__(16) float rnum[16384];  // v4f [w][ii][rep][c4]            (64 KB)
  __shared__ float rden[256];                  // [w][ii*4+h]

  const int t     = threadIdx.x;
  const int i0    = blockIdx.x * 4;
  const int w     = t >> 6;                    // 0..15 = j-tile
  const int lane  = t & 63;
  const int c4    = lane & 31;
  const int rep   = lane >> 5;
  const int hh    = c4 >> 3;

  const int jb = w*64;
  const int j  = jb + lane;

  const float* sA0 = sA + i0*328;              // uniform -> scalar loads
  const float* sA1 = sA0 + 328;
  const float* sA2 = sA0 + 656;
  const float* sA3 = sA0 + 984;
  const float* q0  = q + i0*128;
  const float* q1  = q0 + 128;
  const float* q2  = q0 + 256;
  const float* q3  = q0 + 384;

  const float c00 = sA0[0], c01 = sA0[1], c02 = sA0[2], c03 = sA0[3];
  const float c10 = sA1[0], c11 = sA1[1], c12 = sA1[2], c13 = sA1[3];
  const float c20 = sA2[0], c21 = sA2[1], c22 = sA2[2], c23 = sA2[3];
  const float c30 = sA3[0], c31 = sA3[1], c32 = sA3[2], c33 = sA3[3];
  const float p0x = sA0[4], p0y = sA0[5], p0z = sA0[6];
  const float p1x = sA1[4], p1y = sA1[5], p1z = sA1[6];
  const float p2x = sA2[4], p2y = sA2[5], p2z = sA2[6];
  const float p3x = sA3[4], p3y = sA3[5], p3z = sA3[6];

  const v4f pj = pos4[j];
  const float d0x = p0x-pj.x, d0y = p0y-pj.y, d0z = p0z-pj.z;
  const float d1x = p1x-pj.x, d1y = p1y-pj.y, d1z = p1z-pj.z;
  const float d2x = p2x-pj.x, d2y = p2y-pj.y, d2z = p2z-pj.z;
  const float d3x = p3x-pj.x, d3y = p3y-pj.y, d3z = p3z-pj.z;
  const float dist0 = sqrtf(d0x*d0x + d0y*d0y + d0z*d0z);
  const float dist1 = sqrtf(d1x*d1x + d1y*d1y + d1z*d1z);
  const float dist2 = sqrtf(d2x*d2x + d2y*d2y + d2z*d2z);
  const float dist3 = sqrtf(d3x*d3x + d3y*d3y + d3z*d3z);

  // merged score accumulators: s<row><head>, start at 0; geom then qk add in.
  v2f s0a={0.f,0.f}, s0b={0.f,0.f}, s0c={0.f,0.f}, s0d={0.f,0.f};
  v2f s1a={0.f,0.f}, s1b={0.f,0.f}, s1c={0.f,0.f}, s1d={0.f,0.f};
  v2f s2a={0.f,0.f}, s2b={0.f,0.f}, s2c={0.f,0.f}, s2d={0.f,0.f};
  v2f s3a={0.f,0.f}, s3b={0.f,0.f}, s3c={0.f,0.f}, s3d={0.f,0.f};
  const v2f z = {0.f, 0.f};

  // ---- geom (packed math, bf16 u stream; unpack shared by 4 rows) ----
#define GEOM_ROW(r) { \
    const float* ab = sA##r + 8 + mb*20; \
    const v2f h01 = __builtin_elementwise_max(*(const v2f*)(ab+16) - uj01, z); \
    const v2f h23 = __builtin_elementwise_max(*(const v2f*)(ab+18) - uj23, z); \
    s##r##a = fma2(h01, *(const v2f*)(ab+ 0), s##r##a); s##r##a = fma2(h23, *(const v2f*)(ab+ 2), s##r##a); \
    s##r##b = fma2(h01, *(const v2f*)(ab+ 4), s##r##b); s##r##b = fma2(h23, *(const v2f*)(ab+ 6), s##r##b); \
    s##r##c = fma2(h01, *(const v2f*)(ab+ 8), s##r##c); s##r##c = fma2(h23, *(const v2f*)(ab+10), s##r##c); \
    s##r##d = fma2(h01, *(const v2f*)(ab+12), s##r##d); s##r##d = fma2(h23, *(const v2f*)(ab+14), s##r##d); \
  }
  #pragma unroll 2
  for (int mb = 0; mb < 16; ++mb) {
    const uint2 up_ = uTb[mb*1024 + j];
    const v2f uj01 = unpk(up_.x), uj23 = unpk(up_.y);
    GEOM_ROW(0) GEOM_ROW(1) GEOM_ROW(2) GEOM_ROW(3)
  }
#undef GEOM_ROW

  // ---- qk (packed math, bf16 k stream; unpack shared by 4 rows) ----
#define QK_ROW(r) { \
    const float* qq = q##r + cb*4; \
    s##r##a = fma2(k0a, *(const v2f*)(qq      ), s##r##a); s##r##a = fma2(k0b, *(const v2f*)(qq +  2), s##r##a); \
    s##r##b = fma2(k1a, *(const v2f*)(qq + 32 ), s##r##b); s##r##b = fma2(k1b, *(const v2f*)(qq + 34), s##r##b); \
    s##r##c = fma2(k2a, *(const v2f*)(qq + 64 ), s##r##c); s##r##c = fma2(k2b, *(const v2f*)(qq + 66), s##r##c); \
    s##r##d = fma2(k3a, *(const v2f*)(qq + 96 ), s##r##d); s##r##d = fma2(k3b, *(const v2f*)(qq + 98), s##r##d); \
  }
  #pragma unroll 2
  for (int cb = 0; cb < 8; ++cb) {
    const uint2 kp0 = kTb[(cb     )*1024 + j];
    const uint2 kp1 = kTb[(cb +  8)*1024 + j];
    const uint2 kp2 = kTb[(cb + 16)*1024 + j];
    const uint2 kp3 = kTb[(cb + 24)*1024 + j];
    const v2f k0a = unpk(kp0.x), k0b = unpk(kp0.y);
    const v2f k1a = unpk(kp1.x), k1b = unpk(kp1.y);
    const v2f k2a = unpk(kp2.x), k2b = unpk(kp2.y);
    const v2f k3a = unpk(kp3.x), k3b = unpk(kp3.y);
    QK_ROW(0) QK_ROW(1) QK_ROW(2) QK_ROW(3)
  }
#undef QK_ROW

  // ---- exp2 numerators -> wave-private E ----
  float lsum[16];
  float* eW = &eL[w*1088];
#define EXP_ROW(r, C0, C1, C2, C3, DIST) { \
    const float p0 = exp2f(s##r##a.x + s##r##a.y + (C0 - DIST)); \
    const float p1 = exp2f(s##r##b.x + s##r##b.y + (C1 - DIST)); \
    const float p2 = exp2f(s##r##c.x + s##r##c.y + (C2 - DIST)); \
    const float p3 = exp2f(s##r##d.x + s##r##d.y + (C3 - DIST)); \
    lsum[r*4+0] = p0; lsum[r*4+1] = p1; lsum[r*4+2] = p2; lsum[r*4+3] = p3; \
    eW[(r*4+0)*68 + lane] = p0; eW[(r*4+1)*68 + lane] = p1; \
    eW[(r*4+2)*68 + lane] = p2; eW[(r*4+3)*68 + lane] = p3; \
  }
  EXP_ROW(0, c00, c01, c02, c03, dist0)
  EXP_ROW(1, c10, c11, c12, c13, dist1)
  EXP_ROW(2, c20, c21, c22, c23, dist2)
  EXP_ROW(3, c30, c31, c32, c33, dist3)
#undef EXP_ROW
  __builtin_amdgcn_wave_barrier();

  // ---- denominator reduce first (frees lsum before PV raises pressure) ----
  #pragma unroll
  for (int mm = 1; mm < 64; mm <<= 1) {
    #pragma unroll
    for (int r16 = 0; r16 < 16; ++r16) lsum[r16] += __shfl_xor(lsum[r16], mm);
  }
  if (lane == 0) {
    #pragma unroll
    for (int r16 = 0; r16 < 16; ++r16) rden[w*16 + r16] = lsum[r16];
  }

  // ---- PV: lane owns col-quad c4 (head hh), rep = j-half of tile ----
  v4f acc0 = {0.f,0.f,0.f,0.f};
  v4f acc1 = {0.f,0.f,0.f,0.f};
  v4f acc2 = {0.f,0.f,0.f,0.f};
  v4f acc3 = {0.f,0.f,0.f,0.f};
  {
    const v4f* er0 = (const v4f*)&eL[w*1088 + ( 0 + hh)*68 + rep*32];
    const v4f* er1 = (const v4f*)&eL[w*1088 + ( 4 + hh)*68 + rep*32];
    const v4f* er2 = (const v4f*)&eL[w*1088 + ( 8 + hh)*68 + rep*32];
    const v4f* er3 = (const v4f*)&eL[w*1088 + (12 + hh)*68 + rep*32];
    const v4f* vg = (const v4f*)(v + jb*128);
    const int vbase = rep*32*32 + c4;
    #pragma unroll 2
    for (int jj4 = 0; jj4 < 8; ++jj4) {
      const v4f e0 = er0[jj4];
      const v4f e1 = er1[jj4];
      const v4f e2 = er2[jj4];
      const v4f e3 = er3[jj4];
      const v4f va = vg[vbase + (jj4*4+0)*32];
      const v4f vb = vg[vbase + (jj4*4+1)*32];
      const v4f vc = vg[vbase + (jj4*4+2)*32];
      const v4f vd = vg[vbase + (jj4*4+3)*32];
      acc0 = fma4s(e0.x, va, acc0); acc1 = fma4s(e1.x, va, acc1);
      acc2 = fma4s(e2.x, va, acc2); acc3 = fma4s(e3.x, va, acc3);
      acc0 = fma4s(e0.y, vb, acc0); acc1 = fma4s(e1.y, vb, acc1);
      acc2 = fma4s(e2.y, vb, acc2); acc3 = fma4s(e3.y, vb, acc3);
      acc0 = fma4s(e0.z, vc, acc0); acc1 = fma4s(e1.z, vc, acc1);
      acc2 = fma4s(e2.z, vc, acc2); acc3 = fma4s(e3.z, vc, acc3);
      acc0 = fma4s(e0.w, vd, acc0); acc1 = fma4s(e1.w, vd, acc1);
      acc2 = fma4s(e2.w, vd, acc2); acc3 = fma4s(e3.w, vd, acc3);
    }
  }
  __builtin_amdgcn_wave_barrier();

  // ---- in-block reduce across 16 waves ----
  ((v4f*)rnum)[((w*4+0)*2 + rep)*32 + c4] = acc0;
  ((v4f*)rnum)[((w*4+1)*2 + rep)*32 + c4] = acc1;
  ((v4f*)rnum)[((w*4+2)*2 + rep)*32 + c4] = acc2;
  ((v4f*)rnum)[((w*4+3)*2 + rep)*32 + c4] = acc3;
  __syncthreads();

  if (t < 512) {
    const int ii = t >> 7, c = t & 127;
    float num = 0.f, den = 0.f;
    #pragma unroll
    for (int ww = 0; ww < 16; ++ww) {
      num += rnum[((ww*4+ii)*2+0)*128 + c];
      num += rnum[((ww*4+ii)*2+1)*128 + c];
      den += rden[ww*16 + ii*4 + (c>>5)];
    }
    out[(i0+ii)*128 + c] = num / den;
  }
}

extern "C" void kernel_launch(void* const* d_in, const int* in_sizes, int n_in,
                              void* d_out, int out_size, void* d_ws, size_t ws_size,
                              hipStream_t stream) {
  const float* x   = (const float*)d_in[0];
  const float* y   = (const float*)d_in[1];
  const float* pos = (const float*)d_in[2];
  const float* Wq  = (const float*)d_in[3];
  const float* bq  = (const float*)d_in[4];
  const float* Wk  = (const float*)d_in[5];
  const float* bk  = (const float*)d_in[6];
  const float* Wv  = (const float*)d_in[7];
  const float* bv  = (const float*)d_in[8];
  const float* W1  = (const float*)d_in[9];
  const float* b1  = (const float*)d_in[10];
  const float* W2  = (const float*)d_in[11];
  const float* b2  = (const float*)d_in[12];

  float* ws = (float*)d_ws;
  float*        q    = ws;                              // 131072
  float*        v    = ws + 131072;                     // 131072
  unsigned int* kTb  = (unsigned int*)(ws + 262144);    // 65536 u32
  unsigned int* uTb  = (unsigned int*)(ws + 327680);    // 32768 u32
  float*        sA   = ws + 360448;                     // 335872
  float*        pos4 = ws + 696320;                     // 4096
  float*        out  = (float*)d_out;

  k_pre<<<dim3(512), dim3(384), 0, stream>>>(x, y, pos, Wq, bq, Wk, bk, Wv, bv,
                                             W1, b1, W2, b2,
                                             q, v, kTb, uTb, sA, pos4);
  k_attn<<<dim3(256), dim3(1024), 0, stream>>>(q, v, (const uint2*)kTb,
                                               (const uint2*)uTb, sA,
                                               (const v4f*)pos4, out);
}

// Round 3
// 114.955 us; speedup vs baseline: 1.0474x; 1.0474x over previous
//
#include <hip/hip_runtime.h>
#include <math.h>

// N=1024, C=128, H=4, HD=32, HID=64
//   u[n,m]   = pos[n,:] @ W1[:,m]       (hid[i,j,m] = (u[i,m]+b1[m]) - u[j,m])
//   A[n,h,m] = sum_d q[n,h*32+d] * W2[m, h*32+d]
//   c[n,h]   = sum_d q[n,h*32+d] * b2[h*32+d]
//   score[h,i,j] = (q_i.k_j)/sqrt(32) + sum_m relu(hid)*A[i,h,m] + c[i,h] - dist(i,j)
//   softmax via exp2 (q pre-scaled RS*log2e; A/c/pos pre-scaled log2e)
//
// R13 == R12 with the h2f typedef fixed (__builtin_amdgcn_cvt_pkrtz returns
//   a vector of __fp16, not _Float16; compile error only).
// R12: back to the 2-row/512-block/(1024,8) structure (R11's 4-row variant
//   halved L2 traffic but dropped occupancy 8->4 waves/SIMD and regressed;
//   kernel is latency-bound, not L2-BW-bound). New:
//   - q and k streams stored as packed f16 pairs; QK inner loop uses
//     v_dot2_f32_f16 (one instr replaces unpack+pk_fma; ~15% fewer VALU ops).
//   - geom accumulators collapse to scalars before the qk loop.
//   - denominator shuffle-reduce moved before PV.
//
// ws layout (floats):
//   q    [1024][128] f32 (fallback)  OR  u32[1024][64] f16x2 pairs   @ 0
//   v    [1024][128]                                  @ 131072
//   kTb  u32[32][1024][2]: f16x2 (or bf16x2) k quads  @ 262144
//   uTb  u32[16][1024][2]: bf16x2 u quads             @ 327680
//   sA   [1024][328]                                  @ 360448
//   pos4 [1024][4] (x L2E)                            @ 696320

typedef float v2f __attribute__((ext_vector_type(2)));
typedef float v4f __attribute__((ext_vector_type(4)));
typedef __fp16 h2f __attribute__((ext_vector_type(2)));

#if defined(__has_builtin)
#if __has_builtin(__builtin_amdgcn_fdot2) && __has_builtin(__builtin_amdgcn_cvt_pkrtz)
#define USE_DOT2 1
#endif
#endif

#define L2E 1.4426950408889634f
#define RSL (0.17677669529663687f * L2E)

static __device__ __forceinline__ float dot4(float4 a, float4 b) {
  return a.x*b.x + a.y*b.y + a.z*b.z + a.w*b.w;
}
static __device__ __forceinline__ v2f fma2(v2f a, v2f b, v2f c) {
  return __builtin_elementwise_fma(a, b, c);
}
static __device__ __forceinline__ v4f fma4s(float s, v4f b, v4f c) {
  v4f sv = {s, s, s, s};
  return __builtin_elementwise_fma(sv, b, c);
}
static __device__ __forceinline__ unsigned int bfr(float f) {   // fp32 -> bf16 (RNE)
  unsigned int b = __float_as_uint(f);
  return (b + 0x7fffu + ((b >> 16) & 1u)) >> 16;
}
static __device__ __forceinline__ unsigned int pack2(float lo, float hi) {
  return bfr(lo) | (bfr(hi) << 16);
}
static __device__ __forceinline__ v2f unpk(unsigned int a) {    // bf16x2 -> 2x fp32
  v2f r;
  r.x = __uint_as_float(a << 16);
  r.y = __uint_as_float(a & 0xffff0000u);
  return r;
}
#if USE_DOT2
static __device__ __forceinline__ unsigned int pkh(float lo, float hi) { // 2x f32 -> f16x2 (RTZ)
  h2f r = __builtin_amdgcn_cvt_pkrtz(lo, hi);
  return __builtin_bit_cast(unsigned int, r);
}
static __device__ __forceinline__ float fdot2h(unsigned int k_, unsigned int q_, float acc) {
  return __builtin_amdgcn_fdot2(__builtin_bit_cast(h2f, k_),
                                __builtin_bit_cast(h2f, q_), acc, false);
}
#endif

// ---------------- K1: precompute ------------------------------------------
// 512 blocks x 384 thr; block = 2 rows.
__global__ __launch_bounds__(384) void k_pre(
    const float* __restrict__ x, const float* __restrict__ y, const float* __restrict__ pos,
    const float* __restrict__ Wq, const float* __restrict__ bq,
    const float* __restrict__ Wk, const float* __restrict__ bk,
    const float* __restrict__ Wv, const float* __restrict__ bv,
    const float* __restrict__ W1, const float* __restrict__ b1,
    const float* __restrict__ W2, const float* __restrict__ b2,
    float* __restrict__ q, float* __restrict__ v,
    unsigned int* __restrict__ kTb, unsigned int* __restrict__ uTb,
    float* __restrict__ sA, float* __restrict__ pos4w)
{
  __shared__ float xs[256], ys[256], qs[256];
  __shared__ __align__(16) float4 W2S[64*33];

  const int t  = threadIdx.x;
  const int n0 = blockIdx.x * 2;

  if (t < 256) { xs[t] = x[n0*128 + t]; ys[t] = y[n0*128 + t]; }
  {
    const float4* w2g = (const float4*)W2;
    #pragma unroll
    for (int r = 0; r < 6; ++r) {
      const int e = t + 384*r;
      if (e < 2048) W2S[(e>>5)*33 + (e&31)] = w2g[e];
    }
  }
  __syncthreads();

  {
    const int c   = t & 127;
    const int mat = t >> 7;                 // wave-uniform
    const float* W    = (mat == 0) ? Wq : (mat == 1 ? Wk : Wv);
    const float* S    = (mat == 0) ? xs : ys;
    const float* bias = (mat == 0) ? bq : (mat == 1 ? bk : bv);
    float a0 = 0.f, a1 = 0.f;
    #pragma unroll 8
    for (int d = 0; d < 128; ++d) {
      const float w_ = W[d*128 + c];
      a0 = fmaf(S[d],       w_, a0);
      a1 = fmaf(S[128 + d], w_, a1);
    }
    const float bb = bias[c];
    a0 += bb; a1 += bb;
    if (mat == 0) {
      qs[c] = a0; qs[128 + c] = a1;
#if USE_DOT2
      // q: pack adjacent columns into f16x2 pairs (pre-scaled by RSL)
      const float sa0 = a0 * RSL, sa1 = a1 * RSL;
      const float tb0 = __shfl_xor(sa0, 1);
      const float tb1 = __shfl_xor(sa1, 1);
      if ((c & 1) == 0) {
        unsigned int* qT = (unsigned int*)q;
        qT[(n0  )*64 + (c>>1)] = pkh(sa0, tb0);
        qT[(n0+1)*64 + (c>>1)] = pkh(sa1, tb1);
      }
#else
      q[n0*128 + c] = a0 * RSL; q[(n0+1)*128 + c] = a1 * RSL;
#endif
    } else if (mat == 2) {
      v[n0*128 + c] = a0; v[(n0+1)*128 + c] = a1;
    } else {
      // k: pack adjacent columns into pairs via in-wave exchange
      const float b0 = __shfl_xor(a0, 1);
      const float b1 = __shfl_xor(a1, 1);
      if ((c & 1) == 0) {
        const int idx = ((c>>2)*1024)*2 + ((c>>1)&1);
#if USE_DOT2
        kTb[idx + (n0  )*2] = pkh(a0, b0);
        kTb[idx + (n0+1)*2] = pkh(a1, b1);
#else
        kTb[idx + (n0  )*2] = pack2(a0, b0);
        kTb[idx + (n0+1)*2] = pack2(a1, b1);
#endif
      }
    }
  }
  __syncthreads();

  if (t < 256) {
    const int m = t & 63, h = t >> 6;
    const float4* qs4 = (const float4*)qs;
    #pragma unroll
    for (int ii = 0; ii < 2; ++ii) {
      float acc = 0.f;
      #pragma unroll
      for (int ch = 0; ch < 8; ++ch)
        acc += dot4(qs4[ii*32 + h*8 + ch], W2S[m*33 + h*8 + ch]);
      sA[(n0+ii)*328 + 8 + (m>>2)*20 + h*4 + (m&3)] = acc * L2E;
    }
    if (t < 8) {
      const int ii = t >> 2, h2 = t & 3;
      float ca = 0.f;
      #pragma unroll
      for (int d = 0; d < 32; ++d) ca = fmaf(qs[ii*128 + h2*32 + d], b2[h2*32 + d], ca);
      sA[(n0+ii)*328 + h2] = ca * L2E;
    } else if (t < 16) {
      const int tt = t-8, ii = tt>>2, cc = tt&3;
      sA[(n0+ii)*328 + 4 + cc] = (cc < 3) ? pos[(n0+ii)*3 + cc] * L2E : 0.f;
    } else if (t < 24) {
      const int tt = t-16, ii = tt>>2, cc = tt&3;
      pos4w[(n0+ii)*4 + cc] = (cc < 3) ? pos[(n0+ii)*3 + cc] * L2E : 0.f;
    }
  } else if (t < 320) {
    // u: thread = (ii, m-pair); computes 2 adjacent m -> one bf16x2 word
    const int tt = t - 256, ii = tt >> 5, mp = tt & 31;
    const int m0 = mp * 2;
    float ua0 = 0.f, ua1 = 0.f;
    #pragma unroll
    for (int cc = 0; cc < 3; ++cc) {
      const float p = pos[(n0+ii)*3 + cc];
      ua0 = fmaf(p, W1[cc*64 + m0    ], ua0);
      ua1 = fmaf(p, W1[cc*64 + m0 + 1], ua1);
    }
    sA[(n0+ii)*328 + 8 + (m0>>2)*20 + 16 + (m0&3)    ] = ua0 + b1[m0];
    sA[(n0+ii)*328 + 8 + (m0>>2)*20 + 16 + (m0&3) + 1] = ua1 + b1[m0+1];
    uTb[((mp>>1)*1024 + (n0+ii))*2 + (mp&1)] = pack2(ua0, ua1);
  }
}

// ---------------- K2: fused scores + softmax + PV + direct out -------------
// 512 blocks x 1024 thr (16 waves). Block = 2 i-rows x ALL j; wave w = j-tile w.
__global__ __launch_bounds__(1024, 8) void k_attn(
    const float* __restrict__ q, const float* __restrict__ v,
    const uint2* __restrict__ kTb, const uint2* __restrict__ uTb,
    const float* __restrict__ sA, const v4f* __restrict__ pos4,
    float* __restrict__ out)
{
  __shared__ __align__(16) float eL[16*544];   // per-wave E: [(ii*4+h)*68 + j]
  __shared__ __align__(16) float rnum[8192];   // v4f [w][ii][rep][c4]
  __shared__ float rden[128];                  // [w][ii*4+h]

  const int t     = threadIdx.x;
  const int i0    = blockIdx.x * 2;
  const int w     = t >> 6;                    // 0..15 = j-tile
  const int lane  = t & 63;
  const int c4    = lane & 31;
  const int rep   = lane >> 5;
  const int hh    = c4 >> 3;

  const int jb = w*64;
  const int j  = jb + lane;

  const float* sA0 = sA + i0*328;              // uniform -> scalar loads
  const float* sA1 = sA0 + 328;

  const float c00 = sA0[0], c01 = sA0[1], c02 = sA0[2], c03 = sA0[3];
  const float c10 = sA1[0], c11 = sA1[1], c12 = sA1[2], c13 = sA1[3];
  const float p0x = sA0[4], p0y = sA0[5], p0z = sA0[6];
  const float p1x = sA1[4], p1y = sA1[5], p1z = sA1[6];

  const v4f pj = pos4[j];
  const float d0x = p0x-pj.x, d0y = p0y-pj.y, d0z = p0z-pj.z;
  const float d1x = p1x-pj.x, d1y = p1y-pj.y, d1z = p1z-pj.z;
  const float dist0 = sqrtf(d0x*d0x + d0y*d0y + d0z*d0z);
  const float dist1 = sqrtf(d1x*d1x + d1y*d1y + d1z*d1z);

  // ---- geom (packed math, bf16 u stream) ----
  v2f g0a={0.f,0.f}, g0b={0.f,0.f}, g0c={0.f,0.f}, g0d={0.f,0.f};
  v2f g1a={0.f,0.f}, g1b={0.f,0.f}, g1c={0.f,0.f}, g1d={0.f,0.f};
  #pragma unroll 4
  for (int mb = 0; mb < 16; ++mb) {
    const uint2 up_ = uTb[mb*1024 + j];
    const v2f uj01 = unpk(up_.x), uj23 = unpk(up_.y);
    const v2f z = {0.f, 0.f};
    {
      const float* ab = sA0 + 8 + mb*20;
      const v2f h01 = __builtin_elementwise_max(*(const v2f*)(ab+16) - uj01, z);
      const v2f h23 = __builtin_elementwise_max(*(const v2f*)(ab+18) - uj23, z);
      g0a = fma2(h01, *(const v2f*)(ab+ 0), g0a); g0a = fma2(h23, *(const v2f*)(ab+ 2), g0a);
      g0b = fma2(h01, *(const v2f*)(ab+ 4), g0b); g0b = fma2(h23, *(const v2f*)(ab+ 6), g0b);
      g0c = fma2(h01, *(const v2f*)(ab+ 8), g0c); g0c = fma2(h23, *(const v2f*)(ab+10), g0c);
      g0d = fma2(h01, *(const v2f*)(ab+12), g0d); g0d = fma2(h23, *(const v2f*)(ab+14), g0d);
    }
    {
      const float* ab = sA1 + 8 + mb*20;
      const v2f h01 = __builtin_elementwise_max(*(const v2f*)(ab+16) - uj01, z);
      const v2f h23 = __builtin_elementwise_max(*(const v2f*)(ab+18) - uj23, z);
      g1a = fma2(h01, *(const v2f*)(ab+ 0), g1a); g1a = fma2(h23, *(const v2f*)(ab+ 2), g1a);
      g1b = fma2(h01, *(const v2f*)(ab+ 4), g1b); g1b = fma2(h23, *(const v2f*)(ab+ 6), g1b);
      g1c = fma2(h01, *(const v2f*)(ab+ 8), g1c); g1c = fma2(h23, *(const v2f*)(ab+10), g1c);
      g1d = fma2(h01, *(const v2f*)(ab+12), g1d); g1d = fma2(h23, *(const v2f*)(ab+14), g1d);
    }
  }

#if USE_DOT2
  // collapse geom v2f accumulators to scalars; qk adds into the scalars
  float t0a = g0a.x + g0a.y, t0b = g0b.x + g0b.y;
  float t0c = g0c.x + g0c.y, t0d = g0d.x + g0d.y;
  float t1a = g1a.x + g1a.y, t1b = g1b.x + g1b.y;
  float t1c = g1c.x + g1c.y, t1d = g1d.x + g1d.y;

  // ---- qk via v_dot2_f32_f16 (k and q both packed f16 pairs) ----
  {
    const unsigned int* qT0 = ((const unsigned int*)q) + i0*64;
    const unsigned int* qT1 = qT0 + 64;
    #pragma unroll 8
    for (int cb = 0; cb < 8; ++cb) {
      const uint2 kp0 = kTb[(cb     )*1024 + j];
      const uint2 kp1 = kTb[(cb +  8)*1024 + j];
      const uint2 kp2 = kTb[(cb + 16)*1024 + j];
      const uint2 kp3 = kTb[(cb + 24)*1024 + j];
      t0a = fdot2h(kp0.x, qT0[     cb*2], t0a); t0a = fdot2h(kp0.y, qT0[     cb*2+1], t0a);
      t0b = fdot2h(kp1.x, qT0[16 + cb*2], t0b); t0b = fdot2h(kp1.y, qT0[16 + cb*2+1], t0b);
      t0c = fdot2h(kp2.x, qT0[32 + cb*2], t0c); t0c = fdot2h(kp2.y, qT0[32 + cb*2+1], t0c);
      t0d = fdot2h(kp3.x, qT0[48 + cb*2], t0d); t0d = fdot2h(kp3.y, qT0[48 + cb*2+1], t0d);
      t1a = fdot2h(kp0.x, qT1[     cb*2], t1a); t1a = fdot2h(kp0.y, qT1[     cb*2+1], t1a);
      t1b = fdot2h(kp1.x, qT1[16 + cb*2], t1b); t1b = fdot2h(kp1.y, qT1[16 + cb*2+1], t1b);
      t1c = fdot2h(kp2.x, qT1[32 + cb*2], t1c); t1c = fdot2h(kp2.y, qT1[32 + cb*2+1], t1c);
      t1d = fdot2h(kp3.x, qT1[48 + cb*2], t1d); t1d = fdot2h(kp3.y, qT1[48 + cb*2+1], t1d);
    }
  }

  // ---- exp2 numerators -> wave-private E ----
  float lsum[8];
  float* eW = &eL[w*544];
  {
    const float p0 = exp2f(t0a + (c00 - dist0));
    const float p1 = exp2f(t0b + (c01 - dist0));
    const float p2 = exp2f(t0c + (c02 - dist0));
    const float p3 = exp2f(t0d + (c03 - dist0));
    lsum[0] = p0; lsum[1] = p1; lsum[2] = p2; lsum[3] = p3;
    eW[      lane] = p0; eW[ 68 + lane] = p1; eW[136 + lane] = p2; eW[204 + lane] = p3;
    const float r0 = exp2f(t1a + (c10 - dist1));
    const float r1 = exp2f(t1b + (c11 - dist1));
    const float r2 = exp2f(t1c + (c12 - dist1));
    const float r3 = exp2f(t1d + (c13 - dist1));
    lsum[4] = r0; lsum[5] = r1; lsum[6] = r2; lsum[7] = r3;
    eW[272 + lane] = r0; eW[340 + lane] = r1; eW[408 + lane] = r2; eW[476 + lane] = r3;
  }
#else
  // ---- qk (packed math, bf16 k stream) ----
  v2f s0a={0.f,0.f}, s0b={0.f,0.f}, s0c={0.f,0.f}, s0d={0.f,0.f};
  v2f s1a={0.f,0.f}, s1b={0.f,0.f}, s1c={0.f,0.f}, s1d={0.f,0.f};
  {
    const float* q0 = q + i0*128;
    const float* q1 = q0 + 128;
    #pragma unroll 8
    for (int cb = 0; cb < 8; ++cb) {
      const uint2 kp0 = kTb[(cb     )*1024 + j];
      const uint2 kp1 = kTb[(cb +  8)*1024 + j];
      const uint2 kp2 = kTb[(cb + 16)*1024 + j];
      const uint2 kp3 = kTb[(cb + 24)*1024 + j];
      const v2f k0a = unpk(kp0.x), k0b = unpk(kp0.y);
      const v2f k1a = unpk(kp1.x), k1b = unpk(kp1.y);
      const v2f k2a = unpk(kp2.x), k2b = unpk(kp2.y);
      const v2f k3a = unpk(kp3.x), k3b = unpk(kp3.y);
      s0a = fma2(k0a, *(const v2f*)(q0 + cb*4      ), s0a); s0a = fma2(k0b, *(const v2f*)(q0 + cb*4 +  2), s0a);
      s0b = fma2(k1a, *(const v2f*)(q0 + cb*4 + 32 ), s0b); s0b = fma2(k1b, *(const v2f*)(q0 + cb*4 + 34), s0b);
      s0c = fma2(k2a, *(const v2f*)(q0 + cb*4 + 64 ), s0c); s0c = fma2(k2b, *(const v2f*)(q0 + cb*4 + 66), s0c);
      s0d = fma2(k3a, *(const v2f*)(q0 + cb*4 + 96 ), s0d); s0d = fma2(k3b, *(const v2f*)(q0 + cb*4 + 98), s0d);
      s1a = fma2(k0a, *(const v2f*)(q1 + cb*4      ), s1a); s1a = fma2(k0b, *(const v2f*)(q1 + cb*4 +  2), s1a);
      s1b = fma2(k1a, *(const v2f*)(q1 + cb*4 + 32 ), s1b); s1b = fma2(k1b, *(const v2f*)(q1 + cb*4 + 34), s1b);
      s1c = fma2(k2a, *(const v2f*)(q1 + cb*4 + 64 ), s1c); s1c = fma2(k2b, *(const v2f*)(q1 + cb*4 + 66), s1c);
      s1d = fma2(k3a, *(const v2f*)(q1 + cb*4 + 96 ), s1d); s1d = fma2(k3b, *(const v2f*)(q1 + cb*4 + 98), s1d);
    }
  }

  // ---- exp2 numerators -> wave-private E ----
  float lsum[8];
  float* eW = &eL[w*544];
  {
    const v2f t0a = s0a + g0a, t0b = s0b + g0b, t0c = s0c + g0c, t0d = s0d + g0d;
    const float p0 = exp2f(t0a.x + t0a.y + (c00 - dist0));
    const float p1 = exp2f(t0b.x + t0b.y + (c01 - dist0));
    const float p2 = exp2f(t0c.x + t0c.y + (c02 - dist0));
    const float p3 = exp2f(t0d.x + t0d.y + (c03 - dist0));
    lsum[0] = p0; lsum[1] = p1; lsum[2] = p2; lsum[3] = p3;
    eW[      lane] = p0; eW[ 68 + lane] = p1; eW[136 + lane] = p2; eW[204 + lane] = p3;
    const v2f t1a = s1a + g1a, t1b = s1b + g1b, t1c = s1c + g1c, t1d = s1d + g1d;
    const float r0 = exp2f(t1a.x + t1a.y + (c10 - dist1));
    const float r1 = exp2f(t1b.x + t1b.y + (c11 - dist1));
    const float r2 = exp2f(t1c.x + t1c.y + (c12 - dist1));
    const float r3 = exp2f(t1d.x + t1d.y + (c13 - dist1));
    lsum[4] = r0; lsum[5] = r1; lsum[6] = r2; lsum[7] = r3;
    eW[272 + lane] = r0; eW[340 + lane] = r1; eW[408 + lane] = r2; eW[476 + lane] = r3;
  }
#endif
  __builtin_amdgcn_wave_barrier();

  // ---- denominator reduce first (frees lsum before PV raises pressure) ----
  #pragma unroll
  for (int mm = 1; mm < 64; mm <<= 1) {
    #pragma unroll
    for (int r8 = 0; r8 < 8; ++r8) lsum[r8] += __shfl_xor(lsum[r8], mm);
  }
  if (lane == 0) {
    #pragma unroll
    for (int r8 = 0; r8 < 8; ++r8) rden[w*8 + r8] = lsum[r8];
  }

  // ---- PV: lane owns col-quad c4, rep = j-half of tile (v stays fp32) ----
  v4f acc0 = {0.f,0.f,0.f,0.f};
  v4f acc1 = {0.f,0.f,0.f,0.f};
  {
    const v4f* er0 = (const v4f*)&eL[w*544 +  hh    *68 + rep*32];
    const v4f* er1 = (const v4f*)&eL[w*544 + (4+hh) *68 + rep*32];
    const v4f* vg = (const v4f*)(v + jb*128);
    const int vbase = rep*32*32 + c4;
    #pragma unroll 4
    for (int jj4 = 0; jj4 < 8; ++jj4) {
      const v4f e0 = er0[jj4];
      const v4f e1 = er1[jj4];
      const v4f va = vg[vbase + (jj4*4+0)*32];
      const v4f vb = vg[vbase + (jj4*4+1)*32];
      const v4f vc = vg[vbase + (jj4*4+2)*32];
      const v4f vd = vg[vbase + (jj4*4+3)*32];
      acc0 = fma4s(e0.x, va, acc0); acc1 = fma4s(e1.x, va, acc1);
      acc0 = fma4s(e0.y, vb, acc0); acc1 = fma4s(e1.y, vb, acc1);
      acc0 = fma4s(e0.z, vc, acc0); acc1 = fma4s(e1.z, vc, acc1);
      acc0 = fma4s(e0.w, vd, acc0); acc1 = fma4s(e1.w, vd, acc1);
    }
  }
  __builtin_amdgcn_wave_barrier();

  // ---- in-block reduce across 16 waves ----
  ((v4f*)rnum)[((w*2+0)*2 + rep)*32 + c4] = acc0;
  ((v4f*)rnum)[((w*2+1)*2 + rep)*32 + c4] = acc1;
  __syncthreads();

  if (t < 256) {
    const int ii = t >> 7, c = t & 127;
    float num = 0.f, den = 0.f;
    #pragma unroll
    for (int ww = 0; ww < 16; ++ww) {
      num += rnum[((ww*2+ii)*2+0)*128 + c];
      num += rnum[((ww*2+ii)*2+1)*128 + c];
      den += rden[ww*8 + ii*4 + (c>>5)];
    }
    out[(i0+ii)*128 + c] = num / den;
  }
}

extern "C" void kernel_launch(void* const* d_in, const int* in_sizes, int n_in,
                              void* d_out, int out_size, void* d_ws, size_t ws_size,
                              hipStream_t stream) {
  const float* x   = (const float*)d_in[0];
  const float* y   = (const float*)d_in[1];
  const float* pos = (const float*)d_in[2];
  const float* Wq  = (const float*)d_in[3];
  const float* bq  = (const float*)d_in[4];
  const float* Wk  = (const float*)d_in[5];
  const float* bk  = (const float*)d_in[6];
  const float* Wv  = (const float*)d_in[7];
  const float* bv  = (const float*)d_in[8];
  const float* W1  = (const float*)d_in[9];
  const float* b1  = (const float*)d_in[10];
  const float* W2  = (const float*)d_in[11];
  const float* b2  = (const float*)d_in[12];

  float* ws = (float*)d_ws;
  float*        q    = ws;                              // 131072 (f32) or 65536 u32 (f16x2)
  float*        v    = ws + 131072;                     // 131072
  unsigned int* kTb  = (unsigned int*)(ws + 262144);    // 65536 u32
  unsigned int* uTb  = (unsigned int*)(ws + 327680);    // 32768 u32
  float*        sA   = ws + 360448;                     // 335872
  float*        pos4 = ws + 696320;                     // 4096
  float*        out  = (float*)d_out;

  k_pre<<<dim3(512), dim3(384), 0, stream>>>(x, y, pos, Wq, bq, Wk, bk, Wv, bv,
                                             W1, b1, W2, b2,
                                             q, v, kTb, uTb, sA, pos4);
  k_attn<<<dim3(512), dim3(1024), 0, stream>>>(q, v, (const uint2*)kTb,
                                               (const uint2*)uTb, sA,
                                               (const v4f*)pos4, out);
}